// Round 1
// baseline (346.224 us; speedup 1.0000x reference)
//
#include <hip/hip_runtime.h>
#include <hip/hip_bf16.h>

#define NH 16
#define EHD 64
#define LQ 2048
#define SK 2048
#define QTILE 64
#define KVB 32

typedef __bf16 bf16_t;
typedef bf16_t bf16x8 __attribute__((ext_vector_type(8)));
typedef float f32x4 __attribute__((ext_vector_type(4)));

union BFPack { bf16x8 v; unsigned short u[8]; };

__device__ __forceinline__ unsigned short f2bf(float f){
  unsigned int u = __builtin_bit_cast(unsigned int, f);
  return (unsigned short)((u + 0x7fffu + ((u >> 16) & 1u)) >> 16);
}

__global__ __launch_bounds__(256, 4)
void xattn_fwd(const float* __restrict__ Qg, const float* __restrict__ Kg,
               const float* __restrict__ Vg, const float* __restrict__ Mg,
               float* __restrict__ Og)
{
  // K tile: [32 kv][64 e] bf16, row stride 72 ushorts (144B) -> 2-way banks max
  __shared__ __align__(16) unsigned short Kt[32 * 72];
  // V tile transposed: [64 d][32 kv] bf16, row stride 40 ushorts (80B)
  __shared__ __align__(16) unsigned short Vt[64 * 40];
  // Per-wave P tile: [16 q][32 kv] bf16, row stride 40 ushorts
  __shared__ __align__(16) unsigned short Pt[4][16 * 40];

  const int ltile = blockIdx.x;      // 0..31
  const int bh    = blockIdx.y;      // 0..63  (b*16 + h)
  const int b     = bh >> 4;
  const int h     = bh & 15;
  const int tid   = threadIdx.x;
  const int w     = tid >> 6;        // wave 0..3
  const int lane  = tid & 63;
  const int g     = lane >> 4;       // 16-lane group 0..3
  const int lr    = lane & 15;
  const int qr0   = ltile * QTILE + w * 16;  // wave's first q row

  // ---- Q fragments in registers, pre-scaled by (1/sqrt(64)) * log2(e) ----
  const float qs = 0.125f * 1.44269504088896340736f;
  bf16x8 qfrag[2];
  {
    const float* qp = Qg + ((size_t)b * LQ + qr0 + lr) * 1024 + h * EHD + g * 8;
    #pragma unroll
    for (int c = 0; c < 2; c++) {
      float4 x = *(const float4*)(qp + c * 32);
      float4 y = *(const float4*)(qp + c * 32 + 4);
      BFPack pk;
      pk.u[0] = f2bf(x.x * qs); pk.u[1] = f2bf(x.y * qs);
      pk.u[2] = f2bf(x.z * qs); pk.u[3] = f2bf(x.w * qs);
      pk.u[4] = f2bf(y.x * qs); pk.u[5] = f2bf(y.y * qs);
      pk.u[6] = f2bf(y.z * qs); pk.u[7] = f2bf(y.w * qs);
      qfrag[c] = pk.v;
    }
  }

  // ---- accumulators: acc[dtile][i] covers O[row=g*4+i][d=dtile*16+lr] ----
  f32x4 acc[4];
  #pragma unroll
  for (int dt = 0; dt < 4; dt++) {
    #pragma unroll
    for (int i = 0; i < 4; i++) acc[dt][i] = 0.f;
  }
  float mrun[4], zrun[4];
  #pragma unroll
  for (int i = 0; i < 4; i++) { mrun[i] = -1e30f; zrun[i] = 0.f; }

  // staging roles
  const int kr  = tid >> 3;          // K row 0..31
  const int e0  = (tid & 7) << 3;    // K col base 0..56
  const int vd  = tid & 63;          // V d column 0..63
  const int vk0 = (tid >> 6) << 3;   // V kv base: 0,8,16,24
  const float* kbase = Kg + (size_t)b * SK * 1024 + h * EHD;
  const float* vbase = Vg + (size_t)b * SK * 1024 + h * EHD;

  for (int st = 0; st < SK / KVB; ++st) {
    const int s0 = st * KVB;
    __syncthreads();  // all waves done reading previous K/V tiles

    // ---- stage K tile ----
    {
      const float* kp = kbase + (size_t)(s0 + kr) * 1024 + e0;
      float4 x = *(const float4*)kp;
      float4 y = *(const float4*)(kp + 4);
      BFPack pk;
      pk.u[0] = f2bf(x.x); pk.u[1] = f2bf(x.y); pk.u[2] = f2bf(x.z); pk.u[3] = f2bf(x.w);
      pk.u[4] = f2bf(y.x); pk.u[5] = f2bf(y.y); pk.u[6] = f2bf(y.z); pk.u[7] = f2bf(y.w);
      *(bf16x8*)&Kt[kr * 72 + e0] = pk.v;
    }
    // ---- stage V tile transposed ----
    {
      const float* vp = vbase + (size_t)(s0 + vk0) * 1024 + vd;
      BFPack pk;
      #pragma unroll
      for (int j = 0; j < 8; j++) pk.u[j] = f2bf(vp[(size_t)j * 1024]);
      *(bf16x8*)&Vt[vd * 40 + vk0] = pk.v;
    }
    __syncthreads();

    // ---- QK^T: S[16 q][32 kv] in two D-frags ----
    f32x4 sf0, sf1;
    #pragma unroll
    for (int i = 0; i < 4; i++) { sf0[i] = 0.f; sf1[i] = 0.f; }
    #pragma unroll
    for (int c = 0; c < 2; c++) {
      bf16x8 kb0 = *(const bf16x8*)&Kt[lr * 72 + c * 32 + g * 8];
      sf0 = __builtin_amdgcn_mfma_f32_16x16x32_bf16(qfrag[c], kb0, sf0, 0, 0, 0);
      bf16x8 kb1 = *(const bf16x8*)&Kt[(16 + lr) * 72 + c * 32 + g * 8];
      sf1 = __builtin_amdgcn_mfma_f32_16x16x32_bf16(qfrag[c], kb1, sf1, 0, 0, 0);
    }

    // ---- online softmax; lane holds rows q = g*4 + i ----
    f32x4 rmax;
    #pragma unroll
    for (int i = 0; i < 4; i++) rmax[i] = fmaxf(sf0[i], sf1[i]);
    #pragma unroll
    for (int off = 1; off < 16; off <<= 1) {
      #pragma unroll
      for (int i = 0; i < 4; i++) rmax[i] = fmaxf(rmax[i], __shfl_xor(rmax[i], off));
    }
    float p0[4], p1[4], rs[4], corr[4];
    #pragma unroll
    for (int i = 0; i < 4; i++) {
      float mn = fmaxf(mrun[i], rmax[i]);
      corr[i] = exp2f(mrun[i] - mn);
      mrun[i] = mn;
      p0[i] = exp2f(sf0[i] - mn);
      p1[i] = exp2f(sf1[i] - mn);
      rs[i] = p0[i] + p1[i];
    }
    #pragma unroll
    for (int off = 1; off < 16; off <<= 1) {
      #pragma unroll
      for (int i = 0; i < 4; i++) rs[i] += __shfl_xor(rs[i], off);
    }
    #pragma unroll
    for (int i = 0; i < 4; i++) zrun[i] = zrun[i] * corr[i] + rs[i];
    #pragma unroll
    for (int dt = 0; dt < 4; dt++) {
      #pragma unroll
      for (int i = 0; i < 4; i++) acc[dt][i] *= corr[i];
    }

    // ---- post-softmax multiplicative mask into P (numerator only) ----
    const float* mrow = Mg + (size_t)(qr0 + g * 4) * SK + s0 + lr;
    #pragma unroll
    for (int i = 0; i < 4; i++) {
      float mk0 = mrow[(size_t)i * SK];
      float mk1 = mrow[(size_t)i * SK + 16];
      Pt[w][(g * 4 + i) * 40 + lr]      = f2bf(p0[i] * mk0);
      Pt[w][(g * 4 + i) * 40 + 16 + lr] = f2bf(p1[i] * mk1);
    }

    // ---- PV: O += P[16,32] * V[32,64] (A from per-wave LDS bounce) ----
    bf16x8 pa = *(const bf16x8*)&Pt[w][lr * 40 + g * 8];
    #pragma unroll
    for (int dt = 0; dt < 4; dt++) {
      bf16x8 vb = *(const bf16x8*)&Vt[(dt * 16 + lr) * 40 + g * 8];
      acc[dt] = __builtin_amdgcn_mfma_f32_16x16x32_bf16(pa, vb, acc[dt], 0, 0, 0);
    }
  }

  // ---- epilogue: divide by unmasked denominator; out layout (B,H,L,D) ----
  #pragma unroll
  for (int i = 0; i < 4; i++) {
    float inv = 1.0f / zrun[i];
    float* op = Og + ((size_t)bh * LQ + qr0 + g * 4 + i) * EHD + lr;
    #pragma unroll
    for (int dt = 0; dt < 4; dt++) op[dt * 16] = acc[dt][i] * inv;
  }
}

extern "C" void kernel_launch(void* const* d_in, const int* in_sizes, int n_in,
                              void* d_out, int out_size, void* d_ws, size_t ws_size,
                              hipStream_t stream) {
  const float* Qg = (const float*)d_in[0];
  const float* Kg = (const float*)d_in[1];
  const float* Vg = (const float*)d_in[2];
  const float* Mg = (const float*)d_in[3];
  float* Og = (float*)d_out;
  dim3 grid(LQ / QTILE, 4 * NH);  // x = ltile (K/V L2 reuse), y = b*16+h
  xattn_fwd<<<grid, 256, 0, stream>>>(Qg, Kg, Vg, Mg, Og);
}

// Round 2
// 228.213 us; speedup vs baseline: 1.5171x; 1.5171x over previous
//
#include <hip/hip_runtime.h>
#include <hip/hip_bf16.h>

#define NH 16
#define LQ 2048
#define SK 2048
#define QTILE 64
#define KVB 64
#define KSTR 72   // ushort row stride for all LDS tiles (144 B)

typedef __bf16 bf16_t;
typedef bf16_t bf16x8 __attribute__((ext_vector_type(8)));
typedef bf16_t bf16x4 __attribute__((ext_vector_type(4)));
typedef float f32x4 __attribute__((ext_vector_type(4)));

__device__ __forceinline__ bf16x8 cvt8v(float4 a, float4 b) {
  bf16x8 r;
  r[0] = (bf16_t)a.x; r[1] = (bf16_t)a.y; r[2] = (bf16_t)a.z; r[3] = (bf16_t)a.w;
  r[4] = (bf16_t)b.x; r[5] = (bf16_t)b.y; r[6] = (bf16_t)b.z; r[7] = (bf16_t)b.w;
  return r;
}

__global__ __launch_bounds__(256, 4)
void xattn_fwd(const float* __restrict__ Qg, const float* __restrict__ Kg,
               const float* __restrict__ Vg, const float* __restrict__ Mg,
               float* __restrict__ Og)
{
  __shared__ __align__(16) unsigned short Kt[KVB * KSTR];    // [kv][e]  bf16
  __shared__ __align__(16) unsigned short Vt[64 * KSTR];     // [d][kv]  bf16 (V^T)
  __shared__ __align__(16) unsigned short Pt[4][16 * KSTR];  // per wave [q][kv] bf16

  const int ltile = blockIdx.x;      // 0..31
  const int bh    = blockIdx.y;      // 0..63 (b*16+h)
  const int b     = bh >> 4;
  const int h     = bh & 15;
  const int tid   = threadIdx.x;
  const int w     = tid >> 6;        // wave 0..3
  const int lane  = tid & 63;
  const int g     = lane >> 4;       // group 0..3
  const int lr    = lane & 15;
  const int qr0   = ltile * QTILE + w * 16;  // wave's first q row

  // ---- Q fragments (B-operand layout), pre-scaled by (1/8)*log2(e) ----
  const float qs = 0.125f * 1.44269504088896340736f;
  bf16x8 qfrag[2];
  {
    const float* qp = Qg + ((size_t)b * LQ + qr0 + lr) * 1024 + h * 64 + g * 8;
    #pragma unroll
    for (int c = 0; c < 2; c++) {
      float4 x = *(const float4*)(qp + c * 32);
      float4 y = *(const float4*)(qp + c * 32 + 4);
      x.x *= qs; x.y *= qs; x.z *= qs; x.w *= qs;
      y.x *= qs; y.y *= qs; y.z *= qs; y.w *= qs;
      qfrag[c] = cvt8v(x, y);
    }
  }

  // ---- accumulators: acc[dt] = O^T[d = dt*16 + g*4 + i][q = lr] ----
  f32x4 acc[4];
  #pragma unroll
  for (int dt = 0; dt < 4; dt++)
    #pragma unroll
    for (int i = 0; i < 4; i++) acc[dt][i] = 0.f;
  float mrun = -1e30f;   // running max for q = lr (log2 domain)
  float zrun = 0.f;      // running UNMASKED denominator for q = lr

  // staging roles
  const int kr  = tid >> 3;          // K row 0..31 (and +32)
  const int ke0 = (tid & 7) << 3;    // K col base
  const int vd  = tid & 63;          // V d-column
  const float* kbase = Kg + (size_t)b * SK * 1024 + h * 64;
  const float* vbase = Vg + (size_t)b * SK * 1024 + h * 64;
  const float* mbase = Mg + (size_t)(qr0 + lr) * SK + g * 4;

  for (int s0 = 0; s0 < SK; s0 += KVB) {
    __syncthreads();  // all waves done reading previous K/V tiles

    // ---- stage K tile [64 kv][64 e] ----
    #pragma unroll
    for (int s = 0; s < 2; s++) {
      const float* kp = kbase + (size_t)(s0 + kr + s * 32) * 1024 + ke0;
      float4 a = *(const float4*)kp;
      float4 c4 = *(const float4*)(kp + 4);
      *(bf16x8*)&Kt[(kr + s * 32) * KSTR + ke0] = cvt8v(a, c4);
    }
    // ---- stage V^T tile [64 d][64 kv] ----
    {
      const float* vp = vbase + (size_t)(s0 + w * 16) * 1024 + vd;
      bf16x8 r0, r1;
      #pragma unroll
      for (int j = 0; j < 8; j++) r0[j] = (bf16_t)vp[(size_t)j * 1024];
      #pragma unroll
      for (int j = 0; j < 8; j++) r1[j] = (bf16_t)vp[(size_t)(8 + j) * 1024];
      *(bf16x8*)&Vt[vd * KSTR + w * 16] = r0;
      *(bf16x8*)&Vt[vd * KSTR + w * 16 + 8] = r1;
    }
    __syncthreads();

    // ---- QK^T swapped: sfT[t][r] = S^T[kv = 16t + 4g + r][q = lr] ----
    f32x4 sfT[4];
    #pragma unroll
    for (int t = 0; t < 4; t++)
      #pragma unroll
      for (int r = 0; r < 4; r++) sfT[t][r] = 0.f;
    #pragma unroll
    for (int t = 0; t < 4; t++) {
      #pragma unroll
      for (int c = 0; c < 2; c++) {
        bf16x8 kf = *(const bf16x8*)&Kt[(t * 16 + lr) * KSTR + c * 32 + g * 8];
        sfT[t] = __builtin_amdgcn_mfma_f32_16x16x32_bf16(kf, qfrag[c], sfT[t], 0, 0, 0);
      }
    }

    // ---- online softmax for q = lr (scalar state per lane) ----
    float rmax = sfT[0][0];
    #pragma unroll
    for (int t = 0; t < 4; t++)
      #pragma unroll
      for (int r = 0; r < 4; r++) rmax = fmaxf(rmax, sfT[t][r]);
    rmax = fmaxf(rmax, __shfl_xor(rmax, 16));
    rmax = fmaxf(rmax, __shfl_xor(rmax, 32));

    if (!__all(rmax <= mrun + 6.0f)) {   // defer-rescale (P bounded by 2^6)
      float nm = fmaxf(mrun, rmax);
      float corr = exp2f(mrun - nm);
      mrun = nm;
      zrun *= corr;
      #pragma unroll
      for (int dt = 0; dt < 4; dt++)
        #pragma unroll
        for (int i = 0; i < 4; i++) acc[dt][i] *= corr;
    }

    float rs = 0.f;
    #pragma unroll
    for (int t = 0; t < 4; t++)
      #pragma unroll
      for (int r = 0; r < 4; r++) {
        sfT[t][r] = exp2f(sfT[t][r] - mrun);   // P (pre-mask)
        rs += sfT[t][r];
      }
    rs += __shfl_xor(rs, 16);
    rs += __shfl_xor(rs, 32);
    zrun += rs;   // UNMASKED denominator

    // ---- post-softmax mask into P numerator; pack to LDS (b64 writes) ----
    const float* mp = mbase + s0;
    #pragma unroll
    for (int t = 0; t < 4; t++) {
      float4 mk = *(const float4*)(mp + t * 16);
      bf16x4 pk;
      pk[0] = (bf16_t)(sfT[t][0] * mk.x);
      pk[1] = (bf16_t)(sfT[t][1] * mk.y);
      pk[2] = (bf16_t)(sfT[t][2] * mk.z);
      pk[3] = (bf16_t)(sfT[t][3] * mk.w);
      *(bf16x4*)&Pt[w][lr * KSTR + t * 16 + g * 4] = pk;
    }

    // ---- PV swapped: acc[dt] += V^T[d-tile dt] x P^T  (wave-local Pt) ----
    bf16x8 pb0 = *(const bf16x8*)&Pt[w][lr * KSTR + g * 8];
    bf16x8 pb1 = *(const bf16x8*)&Pt[w][lr * KSTR + 32 + g * 8];
    #pragma unroll
    for (int dt = 0; dt < 4; dt++) {
      bf16x8 vf0 = *(const bf16x8*)&Vt[(dt * 16 + lr) * KSTR + g * 8];
      acc[dt] = __builtin_amdgcn_mfma_f32_16x16x32_bf16(vf0, pb0, acc[dt], 0, 0, 0);
      bf16x8 vf1 = *(const bf16x8*)&Vt[(dt * 16 + lr) * KSTR + 32 + g * 8];
      acc[dt] = __builtin_amdgcn_mfma_f32_16x16x32_bf16(vf1, pb1, acc[dt], 0, 0, 0);
    }
  }

  // ---- epilogue: O[q = lr][d = dt*16 + g*4 + i] / zrun; layout (B,H,L,D) ----
  {
    float inv = 1.0f / zrun;
    float* op = Og + ((size_t)bh * LQ + qr0 + lr) * 64;
    #pragma unroll
    for (int dt = 0; dt < 4; dt++) {
      f32x4 o;
      #pragma unroll
      for (int i = 0; i < 4; i++) o[i] = acc[dt][i] * inv;
      *(f32x4*)(op + dt * 16 + g * 4) = o;
    }
  }
}

extern "C" void kernel_launch(void* const* d_in, const int* in_sizes, int n_in,
                              void* d_out, int out_size, void* d_ws, size_t ws_size,
                              hipStream_t stream) {
  const float* Qg = (const float*)d_in[0];
  const float* Kg = (const float*)d_in[1];
  const float* Vg = (const float*)d_in[2];
  const float* Mg = (const float*)d_in[3];
  float* Og = (float*)d_out;
  dim3 grid(LQ / QTILE, 4 * NH);  // x = ltile (K/V L2 reuse), y = b*16+h
  xattn_fwd<<<grid, 256, 0, stream>>>(Qg, Kg, Vg, Mg, Og);
}

// Round 3
// 220.411 us; speedup vs baseline: 1.5708x; 1.0354x over previous
//
#include <hip/hip_runtime.h>
#include <hip/hip_bf16.h>

#define NH 16
#define LQ 2048
#define SK 2048
#define QTILE 64
#define KVB 64
#define KSTR 72   // ushort row stride for all LDS tiles (144 B)

typedef __bf16 bf16_t;
typedef bf16_t bf16x8 __attribute__((ext_vector_type(8)));
typedef bf16_t bf16x4 __attribute__((ext_vector_type(4)));
typedef float f32x4 __attribute__((ext_vector_type(4)));

__device__ __forceinline__ bf16x8 cvt8v(float4 a, float4 b) {
  bf16x8 r;
  r[0] = (bf16_t)a.x; r[1] = (bf16_t)a.y; r[2] = (bf16_t)a.z; r[3] = (bf16_t)a.w;
  r[4] = (bf16_t)b.x; r[5] = (bf16_t)b.y; r[6] = (bf16_t)b.z; r[7] = (bf16_t)b.w;
  return r;
}

__global__ __launch_bounds__(256, 4)
void xattn_fwd(const float* __restrict__ Qg, const float* __restrict__ Kg,
               const float* __restrict__ Vg, const float* __restrict__ Mg,
               float* __restrict__ Og)
{
  __shared__ __align__(16) unsigned short Kt[KVB * KSTR];    // [kv][e]  bf16
  __shared__ __align__(16) unsigned short Vt[64 * KSTR];     // [d][kv]  bf16 (V^T)
  __shared__ __align__(16) unsigned short Pt[4][16 * KSTR];  // per wave [q][kv] bf16

  const int ltile = blockIdx.x;      // 0..31
  const int bh    = blockIdx.y;      // 0..63 (b*16+h)
  const int b     = bh >> 4;
  const int h     = bh & 15;
  const int tid   = threadIdx.x;
  const int w     = tid >> 6;        // wave 0..3
  const int lane  = tid & 63;
  const int g     = lane >> 4;       // group 0..3
  const int lr    = lane & 15;
  const int qr0   = ltile * QTILE + w * 16;  // wave's first q row

  // ---- Q fragments (B-operand layout), pre-scaled by (1/8)*log2(e) ----
  const float qs = 0.125f * 1.44269504088896340736f;
  bf16x8 qfrag[2];
  {
    const float* qp = Qg + ((size_t)b * LQ + qr0 + lr) * 1024 + h * 64 + g * 8;
    #pragma unroll
    for (int c = 0; c < 2; c++) {
      float4 x = *(const float4*)(qp + c * 32);
      float4 y = *(const float4*)(qp + c * 32 + 4);
      x.x *= qs; x.y *= qs; x.z *= qs; x.w *= qs;
      y.x *= qs; y.y *= qs; y.z *= qs; y.w *= qs;
      qfrag[c] = cvt8v(x, y);
    }
  }

  // ---- accumulators: acc[dt] = O^T[d = dt*16 + g*4 + i][q = lr] ----
  f32x4 acc[4];
  #pragma unroll
  for (int dt = 0; dt < 4; dt++)
    #pragma unroll
    for (int i = 0; i < 4; i++) acc[dt][i] = 0.f;
  float mrun = -1e30f;   // running max for q = lr (log2 domain)
  float zrun = 0.f;      // running UNMASKED denominator for q = lr

  // staging roles
  const int kr  = tid >> 3;          // K row 0..31 (and +32)
  const int ke0 = (tid & 7) << 3;    // K col base
  const int vd  = tid & 63;          // V d-column
  const float* kbase = Kg + (size_t)b * SK * 1024 + h * 64;
  const float* vbase = Vg + (size_t)b * SK * 1024 + h * 64;
  const float* mbase = Mg + (size_t)(qr0 + lr) * SK + g * 4;

  // ---- T14 prefetch registers (tile t+1 lives here during compute of t) ----
  float4 k0a, k0b, k1a, k1b;
  float vr[16];

  // prologue: issue loads for tile 0
  {
    const float* kp0 = kbase + (size_t)kr * 1024 + ke0;
    k0a = *(const float4*)kp0;       k0b = *(const float4*)(kp0 + 4);
    const float* kp1 = kbase + (size_t)(kr + 32) * 1024 + ke0;
    k1a = *(const float4*)kp1;       k1b = *(const float4*)(kp1 + 4);
    const float* vp = vbase + (size_t)(w * 16) * 1024 + vd;
    #pragma unroll
    for (int j = 0; j < 16; j++) vr[j] = vp[(size_t)j * 1024];
  }

  for (int s0 = 0; s0 < SK; s0 += KVB) {
    // ---- cvt staged regs to bf16 (waits on loads issued last iteration) ----
    bf16x8 kc0 = cvt8v(k0a, k0b);
    bf16x8 kc1 = cvt8v(k1a, k1b);
    bf16x8 vc0, vc1;
    #pragma unroll
    for (int j = 0; j < 8; j++) { vc0[j] = (bf16_t)vr[j]; vc1[j] = (bf16_t)vr[8 + j]; }

    __syncthreads();  // all waves done reading previous K/V tiles
    *(bf16x8*)&Kt[kr * KSTR + ke0] = kc0;
    *(bf16x8*)&Kt[(kr + 32) * KSTR + ke0] = kc1;
    *(bf16x8*)&Vt[vd * KSTR + w * 16] = vc0;
    *(bf16x8*)&Vt[vd * KSTR + w * 16 + 8] = vc1;
    __syncthreads();  // tile visible

    // ---- issue mask loads for THIS tile (oldest in vmem queue) ----
    float4 mk0 = *(const float4*)(mbase + s0);
    float4 mk1 = *(const float4*)(mbase + s0 + 16);
    float4 mk2 = *(const float4*)(mbase + s0 + 32);
    float4 mk3 = *(const float4*)(mbase + s0 + 48);

    // ---- issue K/V loads for NEXT tile (in flight across all of compute) ----
    if (s0 + KVB < SK) {
      const float* kp0 = kbase + (size_t)(s0 + KVB + kr) * 1024 + ke0;
      k0a = *(const float4*)kp0;     k0b = *(const float4*)(kp0 + 4);
      const float* kp1 = kbase + (size_t)(s0 + KVB + kr + 32) * 1024 + ke0;
      k1a = *(const float4*)kp1;     k1b = *(const float4*)(kp1 + 4);
      const float* vp = vbase + (size_t)(s0 + KVB + w * 16) * 1024 + vd;
      #pragma unroll
      for (int j = 0; j < 16; j++) vr[j] = vp[(size_t)j * 1024];
    }

    // ---- QK^T swapped: sfT[t][r] = S^T[kv = 16t + 4g + r][q = lr] ----
    f32x4 sfT[4];
    #pragma unroll
    for (int t = 0; t < 4; t++)
      #pragma unroll
      for (int r = 0; r < 4; r++) sfT[t][r] = 0.f;
    #pragma unroll
    for (int t = 0; t < 4; t++) {
      #pragma unroll
      for (int c = 0; c < 2; c++) {
        bf16x8 kf = *(const bf16x8*)&Kt[(t * 16 + lr) * KSTR + c * 32 + g * 8];
        sfT[t] = __builtin_amdgcn_mfma_f32_16x16x32_bf16(kf, qfrag[c], sfT[t], 0, 0, 0);
      }
    }

    // ---- online softmax for q = lr (scalar state per lane) ----
    float rmax = sfT[0][0];
    #pragma unroll
    for (int t = 0; t < 4; t++)
      #pragma unroll
      for (int r = 0; r < 4; r++) rmax = fmaxf(rmax, sfT[t][r]);
    rmax = fmaxf(rmax, __shfl_xor(rmax, 16));
    rmax = fmaxf(rmax, __shfl_xor(rmax, 32));

    if (!__all(rmax <= mrun + 6.0f)) {   // defer-rescale (P bounded by 2^6)
      float nm = fmaxf(mrun, rmax);
      float corr = exp2f(mrun - nm);
      mrun = nm;
      zrun *= corr;
      #pragma unroll
      for (int dt = 0; dt < 4; dt++)
        #pragma unroll
        for (int i = 0; i < 4; i++) acc[dt][i] *= corr;
    }

    float rs = 0.f;
    #pragma unroll
    for (int t = 0; t < 4; t++)
      #pragma unroll
      for (int r = 0; r < 4; r++) {
        sfT[t][r] = exp2f(sfT[t][r] - mrun);   // P (pre-mask)
        rs += sfT[t][r];
      }
    rs += __shfl_xor(rs, 16);
    rs += __shfl_xor(rs, 32);
    zrun += rs;   // UNMASKED denominator

    // ---- post-softmax mask into P numerator; pack to LDS (b64 writes) ----
    {
      bf16x4 pk;
      pk[0] = (bf16_t)(sfT[0][0] * mk0.x); pk[1] = (bf16_t)(sfT[0][1] * mk0.y);
      pk[2] = (bf16_t)(sfT[0][2] * mk0.z); pk[3] = (bf16_t)(sfT[0][3] * mk0.w);
      *(bf16x4*)&Pt[w][lr * KSTR + 0 * 16 + g * 4] = pk;
      pk[0] = (bf16_t)(sfT[1][0] * mk1.x); pk[1] = (bf16_t)(sfT[1][1] * mk1.y);
      pk[2] = (bf16_t)(sfT[1][2] * mk1.z); pk[3] = (bf16_t)(sfT[1][3] * mk1.w);
      *(bf16x4*)&Pt[w][lr * KSTR + 1 * 16 + g * 4] = pk;
      pk[0] = (bf16_t)(sfT[2][0] * mk2.x); pk[1] = (bf16_t)(sfT[2][1] * mk2.y);
      pk[2] = (bf16_t)(sfT[2][2] * mk2.z); pk[3] = (bf16_t)(sfT[2][3] * mk2.w);
      *(bf16x4*)&Pt[w][lr * KSTR + 2 * 16 + g * 4] = pk;
      pk[0] = (bf16_t)(sfT[3][0] * mk3.x); pk[1] = (bf16_t)(sfT[3][1] * mk3.y);
      pk[2] = (bf16_t)(sfT[3][2] * mk3.z); pk[3] = (bf16_t)(sfT[3][3] * mk3.w);
      *(bf16x4*)&Pt[w][lr * KSTR + 3 * 16 + g * 4] = pk;
    }

    // ---- PV swapped: acc[dt] += V^T[d-tile dt] x P^T  (wave-local Pt) ----
    bf16x8 pb0 = *(const bf16x8*)&Pt[w][lr * KSTR + g * 8];
    bf16x8 pb1 = *(const bf16x8*)&Pt[w][lr * KSTR + 32 + g * 8];
    #pragma unroll
    for (int dt = 0; dt < 4; dt++) {
      bf16x8 vf0 = *(const bf16x8*)&Vt[(dt * 16 + lr) * KSTR + g * 8];
      acc[dt] = __builtin_amdgcn_mfma_f32_16x16x32_bf16(vf0, pb0, acc[dt], 0, 0, 0);
      bf16x8 vf1 = *(const bf16x8*)&Vt[(dt * 16 + lr) * KSTR + 32 + g * 8];
      acc[dt] = __builtin_amdgcn_mfma_f32_16x16x32_bf16(vf1, pb1, acc[dt], 0, 0, 0);
    }
  }

  // ---- epilogue: O[q = lr][d = dt*16 + g*4 + i] / zrun; layout (B,H,L,D) ----
  {
    float inv = 1.0f / zrun;
    float* op = Og + ((size_t)bh * LQ + qr0 + lr) * 64;
    #pragma unroll
    for (int dt = 0; dt < 4; dt++) {
      f32x4 o;
      #pragma unroll
      for (int i = 0; i < 4; i++) o[i] = acc[dt][i] * inv;
      *(f32x4*)(op + dt * 16 + g * 4) = o;
    }
  }
}

extern "C" void kernel_launch(void* const* d_in, const int* in_sizes, int n_in,
                              void* d_out, int out_size, void* d_ws, size_t ws_size,
                              hipStream_t stream) {
  const float* Qg = (const float*)d_in[0];
  const float* Kg = (const float*)d_in[1];
  const float* Vg = (const float*)d_in[2];
  const float* Mg = (const float*)d_in[3];
  float* Og = (float*)d_out;
  dim3 grid(LQ / QTILE, 4 * NH);  // x = ltile (K/V L2 reuse), y = b*16+h
  xattn_fwd<<<grid, 256, 0, stream>>>(Qg, Kg, Vg, Mg, Og);
}

// Round 4
// 185.712 us; speedup vs baseline: 1.8643x; 1.1868x over previous
//
#include <hip/hip_runtime.h>
#include <hip/hip_bf16.h>

#define NH 16
#define LQ 2048
#define SK 2048
#define QTILE 128
#define KVB 64
#define KSTR 72   // ushort row stride (144 B): every 8-lane b128 phase is conflict-free

typedef __bf16 bf16_t;
typedef bf16_t bf16x8 __attribute__((ext_vector_type(8)));
typedef bf16_t bf16x2 __attribute__((ext_vector_type(2)));
typedef float f32x16 __attribute__((ext_vector_type(16)));
typedef float f32x4 __attribute__((ext_vector_type(4)));
typedef unsigned int uint2v __attribute__((ext_vector_type(2)));
typedef unsigned int uint4v __attribute__((ext_vector_type(4)));

union U4B8 { uint4v u; bf16x8 v; };

__device__ __forceinline__ bf16x8 cvt8v(f32x4 a, f32x4 b) {
  bf16x8 r;
  r[0]=(bf16_t)a[0]; r[1]=(bf16_t)a[1]; r[2]=(bf16_t)a[2]; r[3]=(bf16_t)a[3];
  r[4]=(bf16_t)b[0]; r[5]=(bf16_t)b[1]; r[6]=(bf16_t)b[2]; r[7]=(bf16_t)b[3];
  return r;
}
__device__ __forceinline__ unsigned pk2(float lo, float hi) {
  bf16x2 t; t[0] = (bf16_t)lo; t[1] = (bf16_t)hi;
  return __builtin_bit_cast(unsigned, t);
}

__global__ __launch_bounds__(256, 2)
void xattn_fwd(const float* __restrict__ Qg, const float* __restrict__ Kg,
               const float* __restrict__ Vg, const float* __restrict__ Mg,
               float* __restrict__ Og)
{
  __shared__ __align__(16) unsigned short Kt[64 * KSTR];  // [kv][e] bf16
  __shared__ __align__(16) unsigned short Vt[64 * KSTR];  // [d][kv] bf16 (V^T)

  // ---- bijective XCD swizzle: all 16 ltiles of one bh land on one XCD ----
  const int f   = blockIdx.x + blockIdx.y * gridDim.x;  // 0..1023
  const int xcd = f & 7;
  const int ii  = f >> 3;          // 0..127
  const int bh  = (xcd << 3) + (ii >> 4);   // 8 bh per XCD
  const int lt  = ii & 15;
  const int b = bh >> 4, h = bh & 15;

  const int tid  = threadIdx.x;
  const int w    = tid >> 6;
  const int lane = tid & 63;
  const int q32  = lane & 31;      // q row within wave tile / A-row / B-col
  const int hi   = lane >> 5;      // 32-lane half
  const int qr0  = lt * QTILE + w * 32;

  // ---- Q B-frags (4 e-chunks), pre-scaled by (1/8)*log2(e) ----
  const float qs = 0.125f * 1.44269504088896340736f;
  bf16x8 qf[4];
  {
    const float* qp = Qg + ((size_t)b * LQ + qr0 + q32) * 1024 + h * 64 + hi * 8;
    #pragma unroll
    for (int ec = 0; ec < 4; ec++) {
      f32x4 x = *(const f32x4*)(qp + ec * 16);
      f32x4 y = *(const f32x4*)(qp + ec * 16 + 4);
      #pragma unroll
      for (int j = 0; j < 4; j++) { x[j] *= qs; y[j] *= qs; }
      qf[ec] = cvt8v(x, y);
    }
  }

  // acc[dt]: O^T[d = 32dt + (m&3)+8(m>>2)+4hi][q = q32]
  f32x16 acc0, acc1;
  #pragma unroll
  for (int m = 0; m < 16; m++) { acc0[m] = 0.f; acc1[m] = 0.f; }
  float mrun = -1e30f, zrun = 0.f;

  // staging roles
  const int kr = tid >> 2;             // K row 0..63
  const int kc = (tid & 3) << 4;       // K col base (floats)
  const int vd = tid & 63;             // V d-column
  const int vk0 = w << 4;              // V kv base per wave
  const float* kbase = Kg + (size_t)b * SK * 1024 + h * 64;
  const float* vbase = Vg + (size_t)b * SK * 1024 + h * 64;
  const float* mbase = Mg + (size_t)(qr0 + q32) * SK + hi * 4;

  // T14 prefetch registers
  f32x4 ka, kb, kc4, kd;
  float vr[16];
  {
    const float* kp = kbase + (size_t)kr * 1024 + kc;
    ka = *(const f32x4*)kp;        kb = *(const f32x4*)(kp + 4);
    kc4 = *(const f32x4*)(kp + 8); kd = *(const f32x4*)(kp + 12);
    const float* vp = vbase + (size_t)vk0 * 1024 + vd;
    #pragma unroll
    for (int j = 0; j < 16; j++) vr[j] = vp[(size_t)j * 1024];
  }

  for (int s0 = 0; s0 < SK; s0 += KVB) {
    // cvt prefetched tile (waits on last iter's loads)
    bf16x8 kcv0 = cvt8v(ka, kb), kcv1 = cvt8v(kc4, kd);
    bf16x8 vcv0, vcv1;
    #pragma unroll
    for (int j = 0; j < 8; j++) { vcv0[j] = (bf16_t)vr[j]; vcv1[j] = (bf16_t)vr[8 + j]; }

    __syncthreads();
    *(bf16x8*)&Kt[kr * KSTR + kc] = kcv0;
    *(bf16x8*)&Kt[kr * KSTR + kc + 8] = kcv1;
    *(bf16x8*)&Vt[vd * KSTR + vk0] = vcv0;
    *(bf16x8*)&Vt[vd * KSTR + vk0 + 8] = vcv1;
    __syncthreads();

    // mask loads for THIS tile: mk[kvt*4+mq] covers kv = s0+32kvt+8mq+4hi+{0..3}
    f32x4 mk[8];
    {
      const float* mp = mbase + s0;
      #pragma unroll
      for (int kvt = 0; kvt < 2; kvt++)
        #pragma unroll
        for (int mq = 0; mq < 4; mq++)
          mk[kvt * 4 + mq] = *(const f32x4*)(mp + kvt * 32 + mq * 8);
    }

    // prefetch next K/V tile
    if (s0 + KVB < SK) {
      const float* kp = kbase + (size_t)(s0 + KVB + kr) * 1024 + kc;
      ka = *(const f32x4*)kp;        kb = *(const f32x4*)(kp + 4);
      kc4 = *(const f32x4*)(kp + 8); kd = *(const f32x4*)(kp + 12);
      const float* vp = vbase + (size_t)(s0 + KVB + vk0) * 1024 + vd;
      #pragma unroll
      for (int j = 0; j < 16; j++) vr[j] = vp[(size_t)j * 1024];
    }

    // ---- QK^T swapped: sT[kvt] = S^T[kv 32-block][q32], 32x32x16 MFMA ----
    f32x16 sT[2];
    #pragma unroll
    for (int m = 0; m < 16; m++) { sT[0][m] = 0.f; sT[1][m] = 0.f; }
    #pragma unroll
    for (int ec = 0; ec < 4; ec++) {
      bf16x8 kf0 = *(const bf16x8*)&Kt[q32 * KSTR + ec * 16 + hi * 8];
      sT[0] = __builtin_amdgcn_mfma_f32_32x32x16_bf16(kf0, qf[ec], sT[0], 0, 0, 0);
      bf16x8 kf1 = *(const bf16x8*)&Kt[(32 + q32) * KSTR + ec * 16 + hi * 8];
      sT[1] = __builtin_amdgcn_mfma_f32_32x32x16_bf16(kf1, qf[ec], sT[1], 0, 0, 0);
    }

    // ---- online softmax for q = q32 (half-row per lane, pair via lane^32) ----
    float rmax = sT[0][0];
    #pragma unroll
    for (int m = 1; m < 16; m++) rmax = fmaxf(rmax, sT[0][m]);
    #pragma unroll
    for (int m = 0; m < 16; m++) rmax = fmaxf(rmax, sT[1][m]);
    rmax = fmaxf(rmax, __shfl_xor(rmax, 32));

    if (!__all(rmax <= mrun + 6.0f)) {   // defer-rescale, P bounded by 2^6
      float nm = fmaxf(mrun, rmax);
      float corr = exp2f(mrun - nm);
      mrun = nm; zrun *= corr;
      #pragma unroll
      for (int m = 0; m < 16; m++) { acc0[m] *= corr; acc1[m] *= corr; }
    }

    float rs = 0.f;
    #pragma unroll
    for (int kvt = 0; kvt < 2; kvt++)
      #pragma unroll
      for (int m = 0; m < 16; m++) { sT[kvt][m] = exp2f(sT[kvt][m] - mrun); rs += sT[kvt][m]; }
    rs += __shfl_xor(rs, 32);
    zrun += rs;   // UNMASKED denominator

    // ---- post-softmax multiplicative mask into numerator ----
    #pragma unroll
    for (int kvt = 0; kvt < 2; kvt++)
      #pragma unroll
      for (int m = 0; m < 16; m++) sT[kvt][m] *= mk[kvt * 4 + (m >> 2)][m & 3];

    // ---- P -> PV B-frags fully in-register: cvt_pk + permlane32_swap ----
    bf16x8 pf[4];
    #pragma unroll
    for (int kvt = 0; kvt < 2; kvt++) {
      #pragma unroll
      for (int c = 0; c < 2; c++) {
        unsigned a0 = pk2(sT[kvt][8 * c + 0], sT[kvt][8 * c + 1]);
        unsigned a1 = pk2(sT[kvt][8 * c + 2], sT[kvt][8 * c + 3]);
        unsigned b0 = pk2(sT[kvt][8 * c + 4], sT[kvt][8 * c + 5]);
        unsigned b1 = pk2(sT[kvt][8 * c + 6], sT[kvt][8 * c + 7]);
        uint2v r02 = __builtin_amdgcn_permlane32_swap(a0, b0, false, false);
        uint2v r13 = __builtin_amdgcn_permlane32_swap(a1, b1, false, false);
        U4B8 u; u.u = uint4v{r02[0], r13[0], r02[1], r13[1]};
        pf[kvt * 2 + c] = u.v;   // B[k=8hi+j][q32] for kv chunk 16*(2kvt+c)
      }
    }

    // ---- PV swapped: acc[dt] += V^T x P^T ----
    #pragma unroll
    for (int c = 0; c < 4; c++) {
      bf16x8 vf0 = *(const bf16x8*)&Vt[q32 * KSTR + c * 16 + hi * 8];
      acc0 = __builtin_amdgcn_mfma_f32_32x32x16_bf16(vf0, pf[c], acc0, 0, 0, 0);
      bf16x8 vf1 = *(const bf16x8*)&Vt[(32 + q32) * KSTR + c * 16 + hi * 8];
      acc1 = __builtin_amdgcn_mfma_f32_32x32x16_bf16(vf1, pf[c], acc1, 0, 0, 0);
    }
  }

  // ---- epilogue: O[q][d] = acc^T / zrun; out layout (B,H,L,D) ----
  {
    float inv = 1.0f / zrun;
    float* op = Og + ((size_t)bh * LQ + qr0 + q32) * 64 + hi * 4;
    #pragma unroll
    for (int mq = 0; mq < 4; mq++) {
      f32x4 o0, o1;
      #pragma unroll
      for (int r = 0; r < 4; r++) { o0[r] = acc0[4 * mq + r] * inv; o1[r] = acc1[4 * mq + r] * inv; }
      *(f32x4*)(op + mq * 8) = o0;        // d = 8mq + 4hi + r
      *(f32x4*)(op + 32 + mq * 8) = o1;   // d = 32 + 8mq + 4hi + r
    }
  }
}

extern "C" void kernel_launch(void* const* d_in, const int* in_sizes, int n_in,
                              void* d_out, int out_size, void* d_ws, size_t ws_size,
                              hipStream_t stream) {
  const float* Qg = (const float*)d_in[0];
  const float* Kg = (const float*)d_in[1];
  const float* Vg = (const float*)d_in[2];
  const float* Mg = (const float*)d_in[3];
  float* Og = (float*)d_out;
  dim3 grid(LQ / QTILE, 4 * NH);   // 16 x 64 = 1024 blocks
  xattn_fwd<<<grid, 256, 0, stream>>>(Qg, Kg, Vg, Mg, Og);
}